// Round 1
// 165.696 us; speedup vs baseline: 1.1035x; 1.1035x over previous
//
#include <hip/hip_runtime.h>
#include <hip/hip_bf16.h>

// MultiHead attention, MI355X/gfx950. fp32 in/out, bf16 MFMA internals.
// B=2, T=2048, C=1024, H=16, D=64.
// Round 8: attn rewritten. (a) swapped-operand QK^T (mfma(K,Q)) keeps P in
// registers; K rows are PERMUTED at staging (kperm) so exp(S^T) lanes are
// byte-exact 16x16x32 A-fragments for PV -- no Psh, no lgkmcnt(0) drain,
// no cross-lane ops. (b) XOR slot-swizzle (slot ^= row&7) on K/V LDS via
// pre-swizzled per-lane global source addrs (linear global_load_lds dest)
// -> bank-conflict floor. (c) uniform balance by construction: each block
// (4 waves x 16 q-rows) processes chunk c then 31-c sequentially = exactly
// 33 k-tiles per block; grid 512, same-(b,h) blocks share an XCD L2.
//
// ws layout (bf16 elems):
//   xb  [4096][1024]            @ 0          (x as bf16)
//   wt  [3][16][64][1024]       @ 4194304    (= fused Bt [3072][1024])
//   wot [1024][1024]            @ 7340032    (Wo transposed, bf16)
//   qkv Q,K:[h][b*2048+t][d] Vt:[h][b][d][t] @ 8388608  (Q pre-scaled 1/32)
//   att [4096][1024]            @ 20971520
// total 25165824 elems = 48 MB

typedef __hip_bfloat16 bf16;
typedef __bf16 v8bf __attribute__((ext_vector_type(8)));
typedef float  v4f  __attribute__((ext_vector_type(4)));
typedef unsigned long long u64;
typedef unsigned int u32;

#define MFMA16(a, b, c) __builtin_amdgcn_mfma_f32_16x16x32_bf16((a), (b), (c), 0, 0, 0)

__device__ __forceinline__ bf16 f2b(float x) { return __float2bfloat16(x); }
__device__ __forceinline__ __bf16 f2braw(float x) {
  bf16 t = __float2bfloat16(x);
  return *reinterpret_cast<__bf16*>(&t);
}
__device__ __forceinline__ unsigned short f2bu(float x) {
  bf16 t = __float2bfloat16(x);
  return *reinterpret_cast<unsigned short*>(&t);
}

// async global->LDS, 16B per lane; LDS dest = wave-uniform base + lane*16.
__device__ __forceinline__ void load16_lds(const bf16* gptr, const bf16* lptr) {
  __builtin_amdgcn_global_load_lds(
      (const __attribute__((address_space(1))) u32*)gptr,
      (__attribute__((address_space(3))) u32*)lptr, 16, 0, 0);
}

// ---------------------------------------------------------------------------
// Fused prep: [0,2048) cvt_x | [2048,5120) Wq/Wk/Wv transpose | [5120,6144) Wo.
// ---------------------------------------------------------------------------
__global__ __launch_bounds__(256) void prep_kernel(
    const float* __restrict__ x,
    const float* __restrict__ Wq, const float* __restrict__ Wk,
    const float* __restrict__ Wv, const float* __restrict__ Wo,
    bf16* __restrict__ xb, bf16* __restrict__ wt, bf16* __restrict__ wot)
{
  __shared__ float Lt[32][33];
  const int bid = blockIdx.x, tid = threadIdx.x;

  if (bid < 2048) {                        // x fp32 -> bf16
    size_t i = ((size_t)bid * 256 + tid) * 8;
    float4 f0 = *(const float4*)(x + i);
    float4 f1 = *(const float4*)(x + i + 4);
    v8bf v;
    v[0] = f2braw(f0.x); v[1] = f2braw(f0.y); v[2] = f2braw(f0.z); v[3] = f2braw(f0.w);
    v[4] = f2braw(f1.x); v[5] = f2braw(f1.y); v[6] = f2braw(f1.z); v[7] = f2braw(f1.w);
    *(v8bf*)(xb + i) = v;
    return;
  }
  const int tx = tid & 31, ty = tid >> 5;
  if (bid < 5120) {                        // Wq/Wk/Wv [h][1024][64] -> wt [z][64][1024]
    const int idx = bid - 2048;
    const int z = idx >> 6, rem = idx & 63;
    const int p = z >> 4, h = z & 15;
    const float* ib = ((p == 0) ? Wq : (p == 1) ? Wk : Wv) + (size_t)h * 65536;
    bf16* ob = wt + (size_t)z * 65536;
    const int j0 = (rem & 1) * 32, i0 = (rem >> 1) * 32;
    #pragma unroll
    for (int r = 0; r < 4; ++r)
      Lt[ty + 8 * r][tx] = ib[(size_t)(i0 + ty + 8 * r) * 64 + j0 + tx];
    __syncthreads();
    #pragma unroll
    for (int r = 0; r < 4; ++r)
      ob[(size_t)(j0 + ty + 8 * r) * 1024 + i0 + tx] = f2b(Lt[tx][ty + 8 * r]);
  } else {                                 // Wo [1024][1024] -> wot transposed
    const int idx = bid - 5120;
    const int j0 = (idx & 31) * 32, i0 = (idx >> 5) * 32;
    #pragma unroll
    for (int r = 0; r < 4; ++r)
      Lt[ty + 8 * r][tx] = Wo[(size_t)(i0 + ty + 8 * r) * 1024 + j0 + tx];
    __syncthreads();
    #pragma unroll
    for (int r = 0; r < 4; ++r)
      wot[(size_t)(j0 + ty + 8 * r) * 1024 + i0 + tx] = f2b(Lt[tx][ty + 8 * r]);
  }
}

// ---------------------------------------------------------------------------
// Kernel 1: fused QKV GEMM, M=4096 x N=3072, K=1024. 128x128 tile, BK=32,
// double-buffered LDS, ONE barrier per k-step. grid (32 mt, 24 nt).
// Epilogue scatters Q,K ([h][m][d], Q*1/32) and V transposed ([h][b][d][t]).
// ---------------------------------------------------------------------------
__global__ __launch_bounds__(256) void qkv_gemm_kernel(
    const bf16* __restrict__ xb, const bf16* __restrict__ wt,
    bf16* __restrict__ qkv)
{
  __shared__ __align__(16) bf16 Ash[2][128][32];
  __shared__ __align__(16) bf16 Bsh[2][128][32];

  const int mt = blockIdx.x, nt = blockIdx.y;
  const int tid = threadIdx.x, w = tid >> 6, lane = tid & 63;
  const int ln = lane & 15, quad = lane >> 4;
  const int wm = w >> 1, wn = w & 1;
  const int m0 = mt * 128, n0 = nt * 128;

  const v4f vzero = {0.f, 0.f, 0.f, 0.f};
  v4f acc[4][4];
  #pragma unroll
  for (int mf = 0; mf < 4; ++mf)
    #pragma unroll
    for (int nf = 0; nf < 4; ++nf) acc[mf][nf] = vzero;

  const int srow = lane >> 2, sseg = (lane & 3) * 8;
  const bf16* ga = xb + (size_t)(m0 + 32 * w + srow) * 1024 + sseg;
  const bf16* gb = wt + (size_t)(n0 + 32 * w + srow) * 1024 + sseg;

  // prologue: stage k-step 0 into buf 0
  {
    load16_lds(ga,             &Ash[0][32 * w][0]);
    load16_lds(ga + 16 * 1024, &Ash[0][32 * w + 16][0]);
    load16_lds(gb,             &Bsh[0][32 * w][0]);
    load16_lds(gb + 16 * 1024, &Bsh[0][32 * w + 16][0]);
  }

  for (int kt = 0; kt < 32; ++kt) {
    const int buf = kt & 1;
    __syncthreads();                       // publishes buf (drains loads)

    v8bf af[4], bfv[4];
    #pragma unroll
    for (int mf = 0; mf < 4; ++mf)
      af[mf] = *(const v8bf*)&Ash[buf][wm * 64 + mf * 16 + ln][quad * 8];
    #pragma unroll
    for (int nf = 0; nf < 4; ++nf)
      bfv[nf] = *(const v8bf*)&Bsh[buf][wn * 64 + nf * 16 + ln][quad * 8];

    if (kt < 31) {                         // stage kt+1 into other buffer
      const int k0 = (kt + 1) * 32, nb = buf ^ 1;
      load16_lds(ga + k0,             &Ash[nb][32 * w][0]);
      load16_lds(ga + 16 * 1024 + k0, &Ash[nb][32 * w + 16][0]);
      load16_lds(gb + k0,             &Bsh[nb][32 * w][0]);
      load16_lds(gb + 16 * 1024 + k0, &Bsh[nb][32 * w + 16][0]);
    }

    #pragma unroll
    for (int mf = 0; mf < 4; ++mf)
      #pragma unroll
      for (int nf = 0; nf < 4; ++nf)
        acc[mf][nf] = MFMA16(af[mf], bfv[nf], acc[mf][nf]);
  }

  const int jcol0 = n0 + wn * 64;
  const int p = jcol0 >> 10;
  const int h = (jcol0 >> 6) & 15;
  const float scale = (p == 0) ? 0.03125f : 1.0f;

  if (p < 2) {                               // Q, K: [h][m][d]
    bf16* base = qkv + (size_t)p * 4194304 + (size_t)h * 262144;
    #pragma unroll
    for (int mf = 0; mf < 4; ++mf)
      #pragma unroll
      for (int nf = 0; nf < 4; ++nf) {
        int d = nf * 16 + ln;
        #pragma unroll
        for (int r = 0; r < 4; ++r) {
          int m = m0 + wm * 64 + mf * 16 + quad * 4 + r;
          base[(size_t)m * 64 + d] = f2b(acc[mf][nf][r] * scale);
        }
      }
  } else {                                   // V transposed: [h][b][d][t]
    bf16* vb = qkv + (size_t)2 * 4194304 + (size_t)h * 262144;
    #pragma unroll
    for (int mf = 0; mf < 4; ++mf) {
      int mrow = m0 + wm * 64 + mf * 16 + quad * 4;
      int bi = mrow >> 11, t0 = mrow & 2047;
      #pragma unroll
      for (int nf = 0; nf < 4; ++nf) {
        int d = nf * 16 + ln;
        u64 pk = (u64)f2bu(acc[mf][nf][0]) |
                 ((u64)f2bu(acc[mf][nf][1]) << 16) |
                 ((u64)f2bu(acc[mf][nf][2]) << 32) |
                 ((u64)f2bu(acc[mf][nf][3]) << 48);
        *(u64*)(vb + (size_t)bi * 131072 + (size_t)d * 2048 + t0) = pk;
      }
    }
  }
}

// ---------------------------------------------------------------------------
// Kernel 2: causal flash attention, swapped-QK^T in-register softmax.
// Block = 4 waves x 16 q-rows = 64 rows; each block runs chunk c then chunk
// 31-c => exactly 33 k-tiles/block (uniform, no dispatch assumptions).
// K staged row-PERMUTED (kperm) so S^T = mfma(K,Q) lanes, after exp, are the
// byte-exact A-fragments for PV (k = ks*32 + quad*8 + j). K/V LDS tiles are
// [64][64] with XOR slot-swizzle (slot ^= row&7), applied via per-lane
// pre-swizzled global source addrs (global_load_lds dest stays linear).
// Row-sum via mfma(pa, ones). grid 512; grp = fid&31 so same-(b,h) blocks
// share an XCD (K/V working set 2MB/XCD fits L2).
// ---------------------------------------------------------------------------
__global__ __launch_bounds__(256, 2) void attn_kernel(
    const bf16* __restrict__ qkv, bf16* __restrict__ att)
{
  __shared__ __align__(16) bf16 Ksh[2][64][64];   // [buf][perm-row][d, slot-swz]
  __shared__ __align__(16) bf16 Vsh[2][64][64];   // [buf][d][t', slot-swz]

  const int fid = blockIdx.x;              // 0..511
  const int pairid = fid >> 5;             // 0..15
  const int grp = fid & 31;                // fid%8 == grp%8 -> same-grp on same XCD
  const int b = grp >> 4, h = grp & 15;

  const int tid = threadIdx.x, w = tid >> 6, lane = tid & 63;
  const int ln = lane & 15, quad = lane >> 4;

  const bf16* qbase  = qkv + (size_t)h * 262144 + (size_t)b * 131072;
  const bf16* kbase  = qbase + 4194304;
  const bf16* vtbase = qbase + 8388608;    // [d][t], d-stride 2048

  // ---- staging lane constants (wave w stages LDS rows w*16..w*16+15) ----
  const int l8 = lane & 7, r8 = lane >> 3;
  const int slot = l8 ^ r8;                // swizzle: LDS[row][s] = G[row][s^(row&7)]
  const int p0 = w * 16 + r8, p1 = p0 + 8; // LDS rows covered by this lane
  // kperm(p): LDS row p holds K row (p>>5)*32 + ((p>>2)&3)*8 + ((p>>4)&1)*4 + (p&3)
  const int kp0 = (p0 & 32) | ((p0 & 12) << 1) | ((p0 & 16) >> 2) | (p0 & 3);
  const int kp1 = (p1 & 32) | ((p1 & 12) << 1) | ((p1 & 16) >> 2) | (p1 & 3);
  const bf16* gk0 = kbase + kp0 * 64 + slot * 8;
  const bf16* gk1 = kbase + kp1 * 64 + slot * 8;
  const bf16* gv0 = vtbase + (w * 16 + r8) * 2048 + slot * 8;
  const bf16* gv1 = gv0 + 8 * 2048;

  // ---- fragment-read lane constants (element offsets into [64][64]) ----
  const int sw = ln & 7;
  const int c0 = ((quad    ) ^ sw) * 8;    // ks=0: global slot quad
  const int c1 = ((quad + 4) ^ sw) * 8;    // ks=1: global slot 4+quad
  const int rowoff = ln * 64;

  v8bf vone;
  {
    unsigned short u = 0x3F80;             // 1.0 bf16
    __bf16 e = *reinterpret_cast<__bf16*>(&u);
    #pragma unroll
    for (int j = 0; j < 8; ++j) vone[j] = e;
  }
  const v4f vzero = {0.f, 0.f, 0.f, 0.f};
  const float NEG = -30000.0f;

  #define STAGE(KB, BUF) {                                       \
    load16_lds(gk0 + (KB) * 4096, &Ksh[BUF][w * 16][0]);         \
    load16_lds(gk1 + (KB) * 4096, &Ksh[BUF][w * 16 + 8][0]);     \
    load16_lds(gv0 + (KB) * 64,   &Vsh[BUF][w * 16][0]);         \
    load16_lds(gv1 + (KB) * 64,   &Vsh[BUF][w * 16 + 8][0]); }

  #pragma unroll 1
  for (int half = 0; half < 2; ++half) {
    const int mt = half ? (31 - pairid) : pairid;
    const int row0 = mt * 64;
    const int wrow = row0 + w * 16;        // wave's q rows: wrow..wrow+15
    const int qg = wrow + ln;              // this lane's q row (S^T col)

    // Q fragments (B-operand): Q[wrow+ln][ks*32 + quad*8 + j]
    v8bf aq[2];
    #pragma unroll
    for (int ks = 0; ks < 2; ++ks)
      aq[ks] = *(const v8bf*)(qbase + (size_t)(wrow + ln) * 64 + ks * 32 + quad * 8);

    v4f o[4], lacc;
    lacc = vzero;
    #pragma unroll
    for (int dt = 0; dt < 4; ++dt) o[dt] = vzero;

    if (half) __syncthreads();             // prev chunk's LDS reads all done
    STAGE(0, 0)

    const int kb_end = mt;
    for (int kb = 0; kb <= kb_end; ++kb) {
      const int buf = kb & 1;
      __syncthreads();                     // publishes buf (drains loads)

      v8bf kf[2][4], vf[2][4];
      const bf16* kr = &Ksh[buf][0][0];
      const bf16* vr = &Vsh[buf][0][0];
      #pragma unroll
      for (int nf = 0; nf < 4; ++nf) {
        kf[0][nf] = *(const v8bf*)(kr + nf * 1024 + rowoff + c0);
        kf[1][nf] = *(const v8bf*)(kr + nf * 1024 + rowoff + c1);
        vf[0][nf] = *(const v8bf*)(vr + nf * 1024 + rowoff + c0);
        vf[1][nf] = *(const v8bf*)(vr + nf * 1024 + rowoff + c1);
      }

      if (kb < kb_end) STAGE(kb + 1, buf ^ 1)

      // S^T = K . Q^T : D[m = perm'd k][n = q(ln)]
      v4f s[4];
      #pragma unroll
      for (int nf = 0; nf < 4; ++nf) s[nf] = vzero;
      #pragma unroll
      for (int ks = 0; ks < 2; ++ks)
        #pragma unroll
        for (int nf = 0; nf < 4; ++nf)
          s[nf] = MFMA16(kf[ks][nf], aq[ks], s[nf]);

      if (kb == kb_end) {                  // causal mask (diagonal tile)
        #pragma unroll
        for (int nf = 0; nf < 4; ++nf) {
          const int kc = kb * 64 + (nf >> 1) * 32 + quad * 8 + (nf & 1) * 4;
          #pragma unroll
          for (int r = 0; r < 4; ++r)
            if (kc + r > qg) s[nf][r] = NEG;
        }
      }

      // P = exp(S); lane holds P[q=ln][k = ks*32 + quad*8 + (hh*4+r)]
      // == byte-exact 16x16x32 A-fragment for PV. No Psh, no cross-lane.
      v8bf pa[2];
      #pragma unroll
      for (int ks = 0; ks < 2; ++ks)
        #pragma unroll
        for (int hh = 0; hh < 2; ++hh)
          #pragma unroll
          for (int r = 0; r < 4; ++r)
            pa[ks][hh * 4 + r] = f2braw(__expf(s[2 * ks + hh][r]));

      lacc = MFMA16(pa[0], vone, lacc);    // row sums (same C layout as o)
      lacc = MFMA16(pa[1], vone, lacc);
      #pragma unroll
      for (int ks = 0; ks < 2; ++ks)
        #pragma unroll
        for (int dt = 0; dt < 4; ++dt)
          o[dt] = MFMA16(pa[ks], vf[ks][dt], o[dt]);
    }

    // epilogue: normalize, store att[b*2048+q][h*64+d]; q = wrow+quad*4+r
    v4f inv;
    #pragma unroll
    for (int r = 0; r < 4; ++r) inv[r] = 1.0f / lacc[r];
    #pragma unroll
    for (int dt = 0; dt < 4; ++dt)
      #pragma unroll
      for (int r = 0; r < 4; ++r) {
        int m = b * 2048 + wrow + quad * 4 + r;
        att[(size_t)m * 1024 + h * 64 + dt * 16 + ln] = f2b(o[dt][r] * inv[r]);
      }
  }
  #undef STAGE
}

// ---------------------------------------------------------------------------
// Kernel 3: output projection + bias, fp32 out. 128x64 tiles, BK=32,
// double-buffered, ONE barrier per k-step. grid (32 mt, 16 nt).
// ---------------------------------------------------------------------------
__global__ __launch_bounds__(256) void out_gemm_kernel(
    const bf16* __restrict__ att, const bf16* __restrict__ wot,
    const float* __restrict__ bo, float* __restrict__ out)
{
  __shared__ __align__(16) bf16 Ash[2][128][32];
  __shared__ __align__(16) bf16 Bsh[2][64][32];

  const int mt = blockIdx.x, nt = blockIdx.y;
  const int tid = threadIdx.x, w = tid >> 6, lane = tid & 63;
  const int ln = lane & 15, quad = lane >> 4;
  const int wm = w >> 1, wn = w & 1;
  const int m0 = mt * 128, n0 = nt * 64;

  const v4f vzero = {0.f, 0.f, 0.f, 0.f};
  v4f acc[4][2];
  #pragma unroll
  for (int mf = 0; mf < 4; ++mf)
    #pragma unroll
    for (int nf = 0; nf < 2; ++nf) acc[mf][nf] = vzero;

  const int srow = lane >> 2, sseg = (lane & 3) * 8;
  const bf16* ga = att + (size_t)(m0 + 32 * w + srow) * 1024 + sseg;
  const bf16* gb = wot + (size_t)(n0 + 16 * w + srow) * 1024 + sseg;

  {
    load16_lds(ga,             &Ash[0][32 * w][0]);
    load16_lds(ga + 16 * 1024, &Ash[0][32 * w + 16][0]);
    load16_lds(gb,             &Bsh[0][16 * w][0]);
  }

  for (int kt = 0; kt < 32; ++kt) {
    const int buf = kt & 1;
    __syncthreads();

    v8bf af[4], bfv[2];
    #pragma unroll
    for (int mf = 0; mf < 4; ++mf)
      af[mf] = *(const v8bf*)&Ash[buf][wm * 64 + mf * 16 + ln][quad * 8];
    #pragma unroll
    for (int nf = 0; nf < 2; ++nf)
      bfv[nf] = *(const v8bf*)&Bsh[buf][wn * 32 + nf * 16 + ln][quad * 8];

    if (kt < 31) {
      const int k0 = (kt + 1) * 32, nb = buf ^ 1;
      load16_lds(ga + k0,             &Ash[nb][32 * w][0]);
      load16_lds(ga + 16 * 1024 + k0, &Ash[nb][32 * w + 16][0]);
      load16_lds(gb + k0,             &Bsh[nb][16 * w][0]);
    }

    #pragma unroll
    for (int mf = 0; mf < 4; ++mf)
      #pragma unroll
      for (int nf = 0; nf < 2; ++nf)
        acc[mf][nf] = MFMA16(af[mf], bfv[nf], acc[mf][nf]);
  }

  #pragma unroll
  for (int nf = 0; nf < 2; ++nf) {
    int j = n0 + wn * 32 + nf * 16 + ln;
    float bias = bo[j];
    #pragma unroll
    for (int mf = 0; mf < 4; ++mf)
      #pragma unroll
      for (int r = 0; r < 4; ++r) {
        int m = m0 + wm * 64 + mf * 16 + quad * 4 + r;
        out[(size_t)m * 1024 + j] = acc[mf][nf][r] + bias;
      }
  }
}

extern "C" void kernel_launch(void* const* d_in, const int* in_sizes, int n_in,
                              void* d_out, int out_size, void* d_ws, size_t ws_size,
                              hipStream_t stream) {
  const float* x  = (const float*)d_in[0];
  const float* Wq = (const float*)d_in[1];
  const float* Wk = (const float*)d_in[2];
  const float* Wv = (const float*)d_in[3];
  const float* Wo = (const float*)d_in[4];
  const float* bo = (const float*)d_in[5];
  float* out = (float*)d_out;

  bf16* xb  = (bf16*)d_ws;
  bf16* wt  = xb + 4194304;
  bf16* wot = xb + 7340032;
  bf16* qkv = xb + 8388608;
  bf16* att = xb + 20971520;

  prep_kernel<<<6144, 256, 0, stream>>>(x, Wq, Wk, Wv, Wo, xb, wt, wot);
  qkv_gemm_kernel<<<dim3(32, 24), 256, 0, stream>>>(xb, wt, qkv);
  attn_kernel<<<512, 256, 0, stream>>>(qkv, att);
  out_gemm_kernel<<<dim3(32, 16), 256, 0, stream>>>(att, wot, bo, out);
}